// Round 5
// baseline (182.013 us; speedup 1.0000x reference)
//
#include <hip/hip_runtime.h>
#include <hip/hip_fp16.h>

// SoftNCutsLoss on MI355X — R5.
// batch: (4,1,32,32,32) f32, preds: (4,8,32,32,32) f32 -> out: (4,) f32
//
// R5 vs R4 (R4 matched prediction: occupancy-bound, grid-limited at 4 blocks/CU;
// plus ~55us of finalize-kernel/launch overhead outside the main dispatch):
//  - grid 1024 -> 2048: dx window split across block pairs (even/odd dxi).
//    Occupancy ceiling 50% -> ~62% (5-block LDS residency, 8 rounds/CU).
//  - finalize fused via last-block pattern: per-block sums atomicAdd into 64
//    device-scope f32 slots in d_ws; atomic counter elects last block, which
//    reads slots back with atomicAdd(p, 0.0f) (coherent reads, safe across
//    non-coherent per-XCD L2s) and writes out[4]. Second kernel eliminated.
//  - d_ws head (counter + slots) zeroed by hipMemsetAsync (graph-legal).
// Inner loop identical to R4 (proven: absmax 0.0, conflicts ~0).

#define EPS_F 2.220446049250313e-16f

constexpr int TD = 4, TH = 4, TW = 8;      // tile dims (d,h,w)
constexpr int HD = 10, HH = 10, HW = 14;   // halo dims (+3 each side)
constexpr int HVOL = HD * HH * HW;         // 1400 (staging loop bound)
constexpr int SXB = 168;                   // sB d-stride (f32, == 8 mod 32)
constexpr int SYB = 16;                    // sB h-stride
constexpr int NB  = 1672;                  // sB plane size
constexpr int SXH = 160;                   // sPh d-stride (halves)
constexpr int SYH = 16;                    // sPh h-stride
constexpr int PSH = 1600;                  // sPh plane stride (halves)
constexpr int NT = 256;                    // threads per block (4 waves)
constexpr int NBLK = 2048;                 // 4 batches * 256 tiles * 2 dx-halves

// exp(-s^2/16) for s^2 in {0,1,4,9}
#define EX0 1.0f
#define EX1 0.93941306281347578611f
#define EX4 0.77880078307140486825f
#define EX9 0.56978282473092302544f

// HALF: dy split across wave pairs. DXH: dx split across block pairs.
template <int HALF, int DXH>
__device__ __forceinline__ void accum_offsets(const float* __restrict__ sB,
                                              const __half* __restrict__ sPh,
                                              int vownB, int vownH, float b_own,
                                              float acc[9]) {
    constexpr float EXT[10] = {EX0, EX1, 0.f, 0.f, EX4, 0.f, 0.f, 0.f, 0.f, EX9};
    constexpr int NDY = HALF ? 3 : 4;
    constexpr int DYI[4] = {HALF ? 1 : 0, HALF ? 3 : 2, HALF ? 5 : 4, HALF ? 7 : 6};

    for (int dxi = DXH; dxi < 7; dxi += 2) {
        const int dx  = dxi - 3;
        const int dxx = dx * dx;                         // runtime, wave-uniform
        const float wdx = __expf((float)dxx * -0.0625f);
        const int baseB = vownB + (dxi - 3) * SXB;
        const int baseH = vownH + (dxi - 3) * SXH;
#pragma unroll
        for (int yy = 0; yy < NDY; ++yy) {
            const int dyi = DYI[yy];                     // constant after unroll
            const int dy  = dyi - 3;
            const int c2y = dy * dy;
#pragma unroll
            for (int dzi = 0; dzi < 7; ++dzi) {
                const int dz = dzi - 3;
                const int c2 = c2y + dz * dz;            // compile-time
                if (c2 >= 16) continue;                  // folded at compile time
                if (dxx + c2 >= 16) continue;            // uniform scalar branch
                const float wyz = EXT[c2y] * EXT[dz * dz];
                const int nvB = baseB + dy * SYB + dz;
                const int nvH = baseH + dy * SYH + dz;
                const float sb = sB[nvB];
                const float d = b_own - sb;
                const float aff = __expf(d * d * -0.01f) * (wdx * wyz);
                acc[8] += aff;
#pragma unroll
                for (int k = 0; k < 8; ++k)
                    acc[k] += aff * __half2float(sPh[k * PSH + nvH]);
            }
        }
    }
}

__global__ __launch_bounds__(NT, 4)
void softncuts_main(const float* __restrict__ batch,
                    const float* __restrict__ preds,
                    int* __restrict__ counter,       // d_ws word 0 (zeroed)
                    float* __restrict__ accum,       // d_ws words 16..79 (zeroed)
                    float* __restrict__ out) {
    __shared__ float  sB[NB];           // batch halo, f32, swizzled strides
    __shared__ __half sPh[8 * PSH];     // preds halo planes, fp16
    __shared__ float  sRed[4][16];
    __shared__ int    sIsLast;

    const int bid  = blockIdx.x;
    const int bb   = bid >> 9;          // batch index 0..3
    const int dxh  = bid & 1;           // dx half: 0 -> dxi even, 1 -> dxi odd
    const int tile = (bid >> 1) & 255;
    const int tw = tile & 3;            // 0..3  -> w0 = tw*8
    const int th = (tile >> 2) & 7;     // 0..7  -> h0 = th*4
    const int td = tile >> 5;           // 0..7  -> d0 = td*4
    const int d0 = td * TD, h0 = th * TH, w0 = tw * TW;

    const int tid  = threadIdx.x;
    const int half = tid >> 7;          // wave-uniform (waves 0,1 vs 2,3)
    const int vtid = tid & 127;
    const int lw = vtid & 7;            // 0..7
    const int lh = (vtid >> 3) & 3;     // 0..3
    const int ld = vtid >> 5;           // 0..3

    // ---- stage halo tile (OOB -> EPS, matching ConstantPad3d(radius-1, eps)) ----
    const float* bbase = batch + (size_t)bb * 32768;
    const float* pbase = preds + (size_t)bb * 8 * 32768;
    for (int v = tid; v < HVOL; v += NT) {
        int hw_ = v % HW;
        int t   = v / HW;
        int hh_ = t % HH;
        int hd_ = t / HH;
        int fB = hd_ * SXB + hh_ * SYB + hw_;
        int fH = hd_ * SXH + hh_ * SYH + hw_;
        int gd = d0 + hd_ - 3, gh = h0 + hh_ - 3, gw = w0 + hw_ - 3;
        bool in = ((unsigned)gd < 32u) & ((unsigned)gh < 32u) & ((unsigned)gw < 32u);
        int sidx = (gd * 32 + gh) * 32 + gw;
        sB[fB] = in ? bbase[sidx] : EPS_F;
#pragma unroll
        for (int k = 0; k < 8; ++k)
            sPh[k * PSH + fH] = __float2half(in ? pbase[sidx + k * 32768] : 0.f);
    }
    __syncthreads();

    // ---- own voxel values from GLOBAL f32 (full precision for b_own and q) ----
    const int sidx_own = ((d0 + ld) * 32 + (h0 + lh)) * 32 + (w0 + lw);
    const float b_own = bbase[sidx_own];
    float q[8];
#pragma unroll
    for (int k = 0; k < 8; ++k) q[k] = pbase[sidx_own + k * 32768];

    const int vownB = (ld + 3) * SXB + (lh + 3) * SYB + (lw + 3);
    const int vownH = (ld + 3) * SXH + (lh + 3) * SYH + (lw + 3);

    float acc[9];
#pragma unroll
    for (int i = 0; i < 9; ++i) acc[i] = 0.f;

    if (dxh == 0) {
        if (half == 0) accum_offsets<0, 0>(sB, sPh, vownB, vownH, b_own, acc);
        else           accum_offsets<1, 0>(sB, sPh, vownB, vownH, b_own, acc);
    } else {
        if (half == 0) accum_offsets<0, 1>(sB, sPh, vownB, vownH, b_own, acc);
        else           accum_offsets<1, 1>(sB, sPh, vownB, vownH, b_own, acc);
    }

    // ---- per-block partial assocA / assocV ----
    float vals[16];
#pragma unroll
    for (int k = 0; k < 8; ++k) {
        vals[k]     = acc[k] * q[k];
        vals[8 + k] = acc[8] * q[k];
    }

#pragma unroll
    for (int i = 0; i < 16; ++i) {
        float s = vals[i];
        for (int off = 32; off; off >>= 1) s += __shfl_down(s, off);
        vals[i] = s;
    }
    const int wave = tid >> 6;
    const int lane = tid & 63;
    if (lane == 0) {
#pragma unroll
        for (int i = 0; i < 16; ++i) sRed[wave][i] = vals[i];
    }
    __syncthreads();
    if (tid < 16) {
        float v = sRed[0][tid] + sRed[1][tid] + sRed[2][tid] + sRed[3][tid];
        atomicAdd(&accum[bb * 16 + tid], v);   // device-scope, coherent point
    }

    // ---- last-block election + fused finalize ----
    __syncthreads();                    // drains vmcnt: accum atomics visible
    if (tid == 0) {
        __threadfence();
        int old = atomicAdd(counter, 1);
        sIsLast = (old == NBLK - 1);
    }
    __syncthreads();
    if (!sIsLast) return;

    if (tid < 64) {                     // wave 0 only
        __threadfence();
        // coherent read of accum[tid] (atomic -> bypasses stale L1/L2 lines)
        float v = atomicAdd(&accum[tid], 0.0f);
        const int slot = tid & 15;      // 0..7 numer, 8..15 denom
        const float den = __shfl(v, tid + 8, 64);   // valid for slot<8
        float r = (slot < 8) ? v / den : 0.f;
#pragma unroll
        for (int off = 8; off; off >>= 1) r += __shfl_down(r, off, 16);
        if (slot == 0) out[tid >> 4] = 8.0f - r;
    }
}

extern "C" void kernel_launch(void* const* d_in, const int* in_sizes, int n_in,
                              void* d_out, int out_size, void* d_ws, size_t ws_size,
                              hipStream_t stream) {
    const float* batch = (const float*)d_in[0];
    const float* preds = (const float*)d_in[1];
    float* out = (float*)d_out;
    int*   counter = (int*)d_ws;            // word 0
    float* accum   = (float*)d_ws + 16;     // words 16..79 (64 slots)

    // zero counter + accumulator slots (graph-capture legal)
    hipMemsetAsync(d_ws, 0, 384, stream);
    softncuts_main<<<dim3(NBLK), dim3(NT), 0, stream>>>(batch, preds,
                                                        counter, accum, out);
}

// Round 6
// 100.167 us; speedup vs baseline: 1.8171x; 1.8171x over previous
//
#include <hip/hip_runtime.h>
#include <hip/hip_fp16.h>

// SoftNCutsLoss on MI355X — R6.
// batch: (4,1,32,32,32) f32, preds: (4,8,32,32,32) f32 -> out: (4,) f32
//
// R6 model (closed from R4 counters): inner loop is LDS ISSUE-limited —
// 18072 ds-instr/CU at 5.8 cyc = 105K cyc = measured 44 us. Fix: fewer, wider
// LDS instructions. Preds packed 8 x f16 = 16 B/voxel -> ONE ds_read_b128 per
// offset (addr = nv*16, aligned; each 8-lane group covers all 32 banks once ->
// pure multi-phase). Per offset: 9 instrs (52 cyc) -> 2 (b128 ~12 + b32 ~5.8).
// R5 lessons: fused-finalize atomics cost ~86 us (reverted to R4 two-kernel
// structure); total-minus-main ~52 us is fixed harness cost in both variants.

#define EPS_F 2.220446049250313e-16f

constexpr int TD = 4, TH = 4, TW = 8;      // tile dims (d,h,w)
constexpr int HD = 10, HH = 10, HW = 14;   // halo dims (+3 each side)
constexpr int HVOL = HD * HH * HW;         // 1400 (staging loop bound)
constexpr int SXB = 168;                   // halo d-stride (== 8 mod 32)
constexpr int SYB = 16;                    // halo h-stride
constexpr int NB  = 1672;                  // halo plane size (voxel slots)
constexpr int NT = 256;                    // threads per block (4 waves)
constexpr int NBLK = 1024;                 // 4 batches * 256 tiles

// exp(-s^2/16) for s^2 in {0,1,4,9}
#define EX0 1.0f
#define EX1 0.93941306281347578611f
#define EX4 0.77880078307140486825f
#define EX9 0.56978282473092302544f

__device__ __forceinline__ float2 unpack_h2(unsigned u) {
    __half2 h;
    __builtin_memcpy(&h, &u, 4);
    return __half22float2(h);
}

template <int HALF>
__device__ __forceinline__ void accum_offsets(const float* __restrict__ sB,
                                              const uint4* __restrict__ sPk,
                                              int vown, float b_own,
                                              float acc[9]) {
    constexpr float EXT[10] = {EX0, EX1, 0.f, 0.f, EX4, 0.f, 0.f, 0.f, 0.f, EX9};
    constexpr int NDY = HALF ? 3 : 4;
    constexpr int DYI[4] = {HALF ? 1 : 0, HALF ? 3 : 2, HALF ? 5 : 4, HALF ? 7 : 6};

    for (int dxi = 0; dxi < 7; ++dxi) {
        const int dx  = dxi - 3;
        const int dxx = dx * dx;                         // runtime, wave-uniform
        const float wdx = __expf((float)dxx * -0.0625f);
        const int base = vown + (dxi - 3) * SXB;
#pragma unroll
        for (int yy = 0; yy < NDY; ++yy) {
            const int dyi = DYI[yy];                     // constant after unroll
            const int dy  = dyi - 3;
            const int c2y = dy * dy;
#pragma unroll
            for (int dzi = 0; dzi < 7; ++dzi) {
                const int dz = dzi - 3;
                const int c2 = c2y + dz * dz;            // compile-time
                if (c2 >= 16) continue;                  // folded at compile time
                if (dxx + c2 >= 16) continue;            // uniform scalar branch
                const float wyz = EXT[c2y] * EXT[dz * dz];
                const int nv = base + dy * SYB + dz;
                const float sb = sB[nv];
                const uint4 pk = sPk[nv];                // ds_read_b128: 8 classes
                const float d = b_own - sb;
                const float aff = __expf(d * d * -0.01f) * (wdx * wyz);
                acc[8] += aff;
                const float2 f01 = unpack_h2(pk.x);
                const float2 f23 = unpack_h2(pk.y);
                const float2 f45 = unpack_h2(pk.z);
                const float2 f67 = unpack_h2(pk.w);
                acc[0] += aff * f01.x; acc[1] += aff * f01.y;
                acc[2] += aff * f23.x; acc[3] += aff * f23.y;
                acc[4] += aff * f45.x; acc[5] += aff * f45.y;
                acc[6] += aff * f67.x; acc[7] += aff * f67.y;
            }
        }
    }
}

__global__ __launch_bounds__(NT, 4)
void softncuts_main(const float* __restrict__ batch,
                    const float* __restrict__ preds,
                    float* __restrict__ partials) {
    __shared__ float sB[NB];            // batch halo, f32
    __shared__ uint4 sPk[NB];           // preds halo, 8 x f16 packed per voxel
    __shared__ float sRed[4][16];

    const int bid  = blockIdx.x;
    const int bb   = bid >> 8;          // batch index 0..3
    const int tile = bid & 255;
    const int tw = tile & 3;            // 0..3  -> w0 = tw*8
    const int th = (tile >> 2) & 7;     // 0..7  -> h0 = th*4
    const int td = tile >> 5;           // 0..7  -> d0 = td*4
    const int d0 = td * TD, h0 = th * TH, w0 = tw * TW;

    const int tid  = threadIdx.x;
    const int half = tid >> 7;          // wave-uniform (waves 0,1 vs 2,3)
    const int vtid = tid & 127;
    const int lw = vtid & 7;            // 0..7
    const int lh = (vtid >> 3) & 3;     // 0..3
    const int ld = vtid >> 5;           // 0..3

    // ---- stage halo tile (OOB -> EPS, matching ConstantPad3d(radius-1, eps)) ----
    const float* bbase = batch + (size_t)bb * 32768;
    const float* pbase = preds + (size_t)bb * 8 * 32768;
    for (int v = tid; v < HVOL; v += NT) {
        int hw_ = v % HW;
        int t   = v / HW;
        int hh_ = t % HH;
        int hd_ = t / HH;
        int f  = hd_ * SXB + hh_ * SYB + hw_;      // swizzled voxel slot
        int gd = d0 + hd_ - 3, gh = h0 + hh_ - 3, gw = w0 + hw_ - 3;
        bool in = ((unsigned)gd < 32u) & ((unsigned)gh < 32u) & ((unsigned)gw < 32u);
        int sidx = (gd * 32 + gh) * 32 + gw;
        sB[f] = in ? bbase[sidx] : EPS_F;
        unsigned u[4];
#pragma unroll
        for (int k = 0; k < 4; ++k) {
            float a = in ? pbase[sidx + (2 * k) * 32768]     : 0.f;
            float b = in ? pbase[sidx + (2 * k + 1) * 32768] : 0.f;
            unsigned lo = __half_as_ushort(__float2half(a));
            unsigned hi = __half_as_ushort(__float2half(b));
            u[k] = lo | (hi << 16);
        }
        sPk[f] = make_uint4(u[0], u[1], u[2], u[3]);
    }
    __syncthreads();

    // ---- own voxel values from GLOBAL f32 (full precision for b_own and q) ----
    const int sidx_own = ((d0 + ld) * 32 + (h0 + lh)) * 32 + (w0 + lw);
    const float b_own = bbase[sidx_own];
    float q[8];
#pragma unroll
    for (int k = 0; k < 8; ++k) q[k] = pbase[sidx_own + k * 32768];

    const int vown = (ld + 3) * SXB + (lh + 3) * SYB + (lw + 3);

    float acc[9];
#pragma unroll
    for (int i = 0; i < 9; ++i) acc[i] = 0.f;

    if (half == 0) accum_offsets<0>(sB, sPk, vown, b_own, acc);
    else           accum_offsets<1>(sB, sPk, vown, b_own, acc);

    // ---- per-block partial assocA / assocV ----
    float vals[16];
#pragma unroll
    for (int k = 0; k < 8; ++k) {
        vals[k]     = acc[k] * q[k];
        vals[8 + k] = acc[8] * q[k];
    }

#pragma unroll
    for (int i = 0; i < 16; ++i) {
        float s = vals[i];
        for (int off = 32; off; off >>= 1) s += __shfl_down(s, off);
        vals[i] = s;
    }
    const int wave = tid >> 6;
    const int lane = tid & 63;
    if (lane == 0) {
#pragma unroll
        for (int i = 0; i < 16; ++i) sRed[wave][i] = vals[i];
    }
    __syncthreads();
    if (tid < 16) {
        partials[tid * NBLK + bid] =
            sRed[0][tid] + sRed[1][tid] + sRed[2][tid] + sRed[3][tid];
    }
}

__global__ __launch_bounds__(1024)
void softncuts_finalize(const float* __restrict__ partials,
                        float* __restrict__ out) {
    __shared__ float red[64];
    const int tid = threadIdx.x;          // 0..1023
    const int group = tid >> 4;           // 0..63 = bb*16 + slot
    const int j0 = tid & 15;
    const int slot = group & 15;
    const int bb = group >> 4;

    const float* p = partials + slot * NBLK + bb * 256;
    float s = 0.f;
#pragma unroll
    for (int k = 0; k < 16; ++k) s += p[j0 + 16 * k];
    for (int off = 8; off; off >>= 1) s += __shfl_down(s, off, 16);
    if (j0 == 0) red[group] = s;
    __syncthreads();

    if (tid < 4) {
        float accv = 0.f;
#pragma unroll
        for (int k = 0; k < 8; ++k)
            accv += red[tid * 16 + k] / red[tid * 16 + 8 + k];
        out[tid] = 8.0f - accv;
    }
}

extern "C" void kernel_launch(void* const* d_in, const int* in_sizes, int n_in,
                              void* d_out, int out_size, void* d_ws, size_t ws_size,
                              hipStream_t stream) {
    const float* batch = (const float*)d_in[0];
    const float* preds = (const float*)d_in[1];
    float* out      = (float*)d_out;
    float* partials = (float*)d_ws;   // 16*NBLK floats = 64 KB

    softncuts_main<<<dim3(NBLK), dim3(NT), 0, stream>>>(batch, preds, partials);
    softncuts_finalize<<<dim3(1), dim3(1024), 0, stream>>>(partials, out);
}

// Round 7
// 94.347 us; speedup vs baseline: 1.9292x; 1.0617x over previous
//
#include <hip/hip_runtime.h>
#include <hip/hip_fp16.h>

// SoftNCutsLoss on MI355X — R7.
// batch: (4,1,32,32,32) f32, preds: (4,8,32,32,32) f32 -> out: (4,) f32
//
// R7 model (from R4/R6 ledger): LDS pipe ~15us/CU, VALU ~20us/CU busy, measured
// 46.8us with both <50% and OccupancyPercent 31 -> latency-bound, grid-capped at
// 16 waves/CU (50%). Fix concurrency, not instruction count:
//  - 512-thread blocks (8 waves); quarter tid>>7 covers the same 128-voxel tile,
//    offsets split by compile-time class (dyi+dzi)&3 (sizes 62/64/61/64 of 251).
//  - __launch_bounds__(512,8): 4 blocks/CU = 32 waves/CU = 100% ceiling;
//    LDS 4 x 33.7KB = 135KB <= 160KB; VGPR cap 64 (R6 used 52).
//  - grid 1024 = exactly 4 blocks/CU, one round, no tail.
// Inner body identical to R6 (packed 8xf16 preds -> 1 ds_read_b128 + 1 b32).

#define EPS_F 2.220446049250313e-16f

constexpr int TD = 4, TH = 4, TW = 8;      // tile dims (d,h,w)
constexpr int HD = 10, HH = 10, HW = 14;   // halo dims (+3 each side)
constexpr int HVOL = HD * HH * HW;         // 1400 (staging loop bound)
constexpr int SXB = 168;                   // halo d-stride (== 8 mod 32)
constexpr int SYB = 16;                    // halo h-stride
constexpr int NB  = 1672;                  // halo plane size (voxel slots)
constexpr int NT = 512;                    // threads per block (8 waves)
constexpr int NBLK = 1024;                 // 4 batches * 256 tiles

// exp(-s^2/16) for s^2 in {0,1,4,9}
#define EX0 1.0f
#define EX1 0.93941306281347578611f
#define EX4 0.77880078307140486825f
#define EX9 0.56978282473092302544f

__device__ __forceinline__ float2 unpack_h2(unsigned u) {
    __half2 h;
    __builtin_memcpy(&h, &u, 4);
    return __half22float2(h);
}

template <int QT>
__device__ __forceinline__ void accum_offsets(const float* __restrict__ sB,
                                              const uint4* __restrict__ sPk,
                                              int vown, float b_own,
                                              float acc[9]) {
    constexpr float EXT[10] = {EX0, EX1, 0.f, 0.f, EX4, 0.f, 0.f, 0.f, 0.f, EX9};

    for (int dxi = 0; dxi < 7; ++dxi) {
        const int dx  = dxi - 3;
        const int dxx = dx * dx;                         // runtime, wave-uniform
        const float wdx = __expf((float)dxx * -0.0625f);
        const int base = vown + (dxi - 3) * SXB;
#pragma unroll
        for (int dyi = 0; dyi < 7; ++dyi) {
            const int dy  = dyi - 3;
            const int c2y = dy * dy;
#pragma unroll
            for (int dzi = 0; dzi < 7; ++dzi) {
                if (((dyi + dzi) & 3) != QT) continue;   // compile-time class
                const int dz = dzi - 3;
                const int c2 = c2y + dz * dz;            // compile-time
                if (c2 >= 16) continue;                  // folded at compile time
                if (dxx + c2 >= 16) continue;            // uniform scalar branch
                const float wyz = EXT[c2y] * EXT[dz * dz];
                const int nv = base + dy * SYB + dz;
                const float sb = sB[nv];
                const uint4 pk = sPk[nv];                // ds_read_b128: 8 classes
                const float d = b_own - sb;
                const float aff = __expf(d * d * -0.01f) * (wdx * wyz);
                acc[8] += aff;
                const float2 f01 = unpack_h2(pk.x);
                const float2 f23 = unpack_h2(pk.y);
                const float2 f45 = unpack_h2(pk.z);
                const float2 f67 = unpack_h2(pk.w);
                acc[0] += aff * f01.x; acc[1] += aff * f01.y;
                acc[2] += aff * f23.x; acc[3] += aff * f23.y;
                acc[4] += aff * f45.x; acc[5] += aff * f45.y;
                acc[6] += aff * f67.x; acc[7] += aff * f67.y;
            }
        }
    }
}

__global__ __launch_bounds__(NT, 8)
void softncuts_main(const float* __restrict__ batch,
                    const float* __restrict__ preds,
                    float* __restrict__ partials) {
    __shared__ float sB[NB];            // batch halo, f32
    __shared__ uint4 sPk[NB];           // preds halo, 8 x f16 packed per voxel
    __shared__ float sRed[8][16];

    const int bid  = blockIdx.x;
    const int bb   = bid >> 8;          // batch index 0..3
    const int tile = bid & 255;
    const int tw = tile & 3;            // 0..3  -> w0 = tw*8
    const int th = (tile >> 2) & 7;     // 0..7  -> h0 = th*4
    const int td = tile >> 5;           // 0..7  -> d0 = td*4
    const int d0 = td * TD, h0 = th * TH, w0 = tw * TW;

    const int tid  = threadIdx.x;
    const int qt   = tid >> 7;          // wave-pair-uniform quarter 0..3
    const int vtid = tid & 127;
    const int lw = vtid & 7;            // 0..7
    const int lh = (vtid >> 3) & 3;     // 0..3
    const int ld = vtid >> 5;           // 0..3

    // ---- stage halo tile (OOB -> EPS, matching ConstantPad3d(radius-1, eps)) ----
    const float* bbase = batch + (size_t)bb * 32768;
    const float* pbase = preds + (size_t)bb * 8 * 32768;
    for (int v = tid; v < HVOL; v += NT) {
        int hw_ = v % HW;
        int t   = v / HW;
        int hh_ = t % HH;
        int hd_ = t / HH;
        int f  = hd_ * SXB + hh_ * SYB + hw_;      // swizzled voxel slot
        int gd = d0 + hd_ - 3, gh = h0 + hh_ - 3, gw = w0 + hw_ - 3;
        bool in = ((unsigned)gd < 32u) & ((unsigned)gh < 32u) & ((unsigned)gw < 32u);
        int sidx = (gd * 32 + gh) * 32 + gw;
        sB[f] = in ? bbase[sidx] : EPS_F;
        unsigned u[4];
#pragma unroll
        for (int k = 0; k < 4; ++k) {
            float a = in ? pbase[sidx + (2 * k) * 32768]     : 0.f;
            float b = in ? pbase[sidx + (2 * k + 1) * 32768] : 0.f;
            unsigned lo = __half_as_ushort(__float2half(a));
            unsigned hi = __half_as_ushort(__float2half(b));
            u[k] = lo | (hi << 16);
        }
        sPk[f] = make_uint4(u[0], u[1], u[2], u[3]);
    }
    __syncthreads();

    // ---- own voxel values from GLOBAL f32 (full precision for b_own and q) ----
    const int sidx_own = ((d0 + ld) * 32 + (h0 + lh)) * 32 + (w0 + lw);
    const float b_own = bbase[sidx_own];
    float q[8];
#pragma unroll
    for (int k = 0; k < 8; ++k) q[k] = pbase[sidx_own + k * 32768];

    const int vown = (ld + 3) * SXB + (lh + 3) * SYB + (lw + 3);

    float acc[9];
#pragma unroll
    for (int i = 0; i < 9; ++i) acc[i] = 0.f;

    switch (qt) {
        case 0: accum_offsets<0>(sB, sPk, vown, b_own, acc); break;
        case 1: accum_offsets<1>(sB, sPk, vown, b_own, acc); break;
        case 2: accum_offsets<2>(sB, sPk, vown, b_own, acc); break;
        default: accum_offsets<3>(sB, sPk, vown, b_own, acc); break;
    }

    // ---- per-block partial assocA / assocV ----
    float vals[16];
#pragma unroll
    for (int k = 0; k < 8; ++k) {
        vals[k]     = acc[k] * q[k];
        vals[8 + k] = acc[8] * q[k];
    }

#pragma unroll
    for (int i = 0; i < 16; ++i) {
        float s = vals[i];
        for (int off = 32; off; off >>= 1) s += __shfl_down(s, off);
        vals[i] = s;
    }
    const int wave = tid >> 6;
    const int lane = tid & 63;
    if (lane == 0) {
#pragma unroll
        for (int i = 0; i < 16; ++i) sRed[wave][i] = vals[i];
    }
    __syncthreads();
    if (tid < 16) {
        float s = 0.f;
#pragma unroll
        for (int w = 0; w < 8; ++w) s += sRed[w][tid];
        partials[tid * NBLK + bid] = s;
    }
}

__global__ __launch_bounds__(1024)
void softncuts_finalize(const float* __restrict__ partials,
                        float* __restrict__ out) {
    __shared__ float red[64];
    const int tid = threadIdx.x;          // 0..1023
    const int group = tid >> 4;           // 0..63 = bb*16 + slot
    const int j0 = tid & 15;
    const int slot = group & 15;
    const int bb = group >> 4;

    const float* p = partials + slot * NBLK + bb * 256;
    float s = 0.f;
#pragma unroll
    for (int k = 0; k < 16; ++k) s += p[j0 + 16 * k];
    for (int off = 8; off; off >>= 1) s += __shfl_down(s, off, 16);
    if (j0 == 0) red[group] = s;
    __syncthreads();

    if (tid < 4) {
        float accv = 0.f;
#pragma unroll
        for (int k = 0; k < 8; ++k)
            accv += red[tid * 16 + k] / red[tid * 16 + 8 + k];
        out[tid] = 8.0f - accv;
    }
}

extern "C" void kernel_launch(void* const* d_in, const int* in_sizes, int n_in,
                              void* d_out, int out_size, void* d_ws, size_t ws_size,
                              hipStream_t stream) {
    const float* batch = (const float*)d_in[0];
    const float* preds = (const float*)d_in[1];
    float* out      = (float*)d_out;
    float* partials = (float*)d_ws;   // 16*NBLK floats = 64 KB

    softncuts_main<<<dim3(NBLK), dim3(NT), 0, stream>>>(batch, preds, partials);
    softncuts_finalize<<<dim3(1), dim3(1024), 0, stream>>>(partials, out);
}

// Round 9
// 87.084 us; speedup vs baseline: 2.0901x; 1.0834x over previous
//
#include <hip/hip_runtime.h>
#include <hip/hip_fp16.h>

// SoftNCutsLoss on MI355X — R9.
// batch: (4,1,32,32,32) f32, preds: (4,8,32,32,32) f32 -> out: (4,) f32
//
// R9 = R8 (pairwise symmetry, 125 positive offsets, forward-x halo) with the
// pad double-count FIXED: positive-direction OOB pad pairs already accrue in
// acc[8] via the EPS-staged halo, so the geometric pad sum S must cover only
// lexicographically NEGATIVE OOB offsets (dx<0 | (dx==0 & (dy<0 | (dy==0 & dz<0)))).
// R8's absmax 0.219 matched this signature (54% of voxels are border voxels,
// forward pad mass counted twice in assocV).
//
//   assocA[k] = sum_i q^2 + 2 q acc[k]           (acc over positive offsets)
//   assocV[k] = sum_i q (acc[8] + 1 + S e(b)) + acc[k]
// R7 lessons kept: occupancy not the lever; launch_bounds(256,4), no spills.

#define EPS_F 2.220446049250313e-16f

constexpr int TD = 4, TH = 4, TW = 8;      // tile dims (d,h,w)
constexpr int HD = 7, HH = 10, HW = 14;    // halo: x forward-only +3, y/z +-3
constexpr int HVOL = HD * HH * HW;         // 980 (staging loop bound)
constexpr int SXB = 168;                   // halo d-stride (== 8 mod 32)
constexpr int SYB = 16;                    // halo h-stride
constexpr int NB  = 6 * SXB + 9 * SYB + 13 + 1;  // 1166 voxel slots
constexpr int NT = 256;                    // threads per block (4 waves)
constexpr int NBLK = 1024;                 // 4 batches * 256 tiles

// exp(-s^2/16) for s^2 in {0,1,4,9}
#define EX0 1.0f
#define EX1 0.93941306281347578611f
#define EX4 0.77880078307140486825f
#define EX9 0.56978282473092302544f

__device__ __forceinline__ float2 unpack_h2(unsigned u) {
    __half2 h;
    __builtin_memcpy(&h, &u, 4);
    return __half22float2(h);
}

// Positive (lexicographic) offsets only: dx>0, or dx==0 && (dy>0 || (dy==0 && dz>0)).
// HALF: parity split (dyi+dzi)&1 across wave pairs (~62/63 of 125).
template <int HALF>
__device__ __forceinline__ void accum_pairs(const float* __restrict__ sB,
                                            const uint4* __restrict__ sPk,
                                            int vown, float b_own,
                                            float acc[9]) {
    constexpr float EXT[10] = {EX0, EX1, 0.f, 0.f, EX4, 0.f, 0.f, 0.f, 0.f, EX9};
#pragma unroll
    for (int dxq = 0; dxq < 4; ++dxq) {             // dx = 0..3 (forward only)
        const int base = vown + dxq * SXB;
#pragma unroll
        for (int dyi = 0; dyi < 7; ++dyi) {
            const int dy = dyi - 3;
#pragma unroll
            for (int dzi = 0; dzi < 7; ++dzi) {
                const int dz = dzi - 3;
                if (dxq == 0) {                      // lexicographic positivity
                    if (dy < 0) continue;
                    if (dy == 0 && dz <= 0) continue;
                }
                const int c2 = dxq * dxq + dy * dy + dz * dz;
                if (c2 >= 16) continue;              // ball cutoff (compile-time)
                if (((dyi + dzi) & 1) != HALF) continue;
                const float w = EXT[dxq * dxq] * EXT[dy * dy] * EXT[dz * dz];
                const int nv = base + dy * SYB + dz; // positive immediate
                const float sb = sB[nv];
                const uint4 pk = sPk[nv];            // ds_read_b128: 8 classes
                const float d = b_own - sb;
                const float aff = __expf(d * d * -0.01f) * w;
                acc[8] += aff;
                const float2 f01 = unpack_h2(pk.x);
                const float2 f23 = unpack_h2(pk.y);
                const float2 f45 = unpack_h2(pk.z);
                const float2 f67 = unpack_h2(pk.w);
                acc[0] += aff * f01.x; acc[1] += aff * f01.y;
                acc[2] += aff * f23.x; acc[3] += aff * f23.y;
                acc[4] += aff * f45.x; acc[5] += aff * f45.y;
                acc[6] += aff * f67.x; acc[7] += aff * f67.y;
            }
        }
    }
}

__global__ __launch_bounds__(NT, 4)
void softncuts_main(const float* __restrict__ batch,
                    const float* __restrict__ preds,
                    float* __restrict__ partials) {
    __shared__ float sB[NB];            // batch halo, f32
    __shared__ uint4 sPk[NB];           // preds halo, 8 x f16 packed per voxel
    __shared__ float sRed[4][16];

    const int bid  = blockIdx.x;
    const int bb   = bid >> 8;          // batch index 0..3
    const int tile = bid & 255;
    const int tw = tile & 3;            // 0..3  -> w0 = tw*8
    const int th = (tile >> 2) & 7;     // 0..7  -> h0 = th*4
    const int td = tile >> 5;           // 0..7  -> d0 = td*4
    const int d0 = td * TD, h0 = th * TH, w0 = tw * TW;

    const int tid  = threadIdx.x;
    const int half = tid >> 7;          // wave-pair-uniform 0/1
    const int vtid = tid & 127;
    const int lw = vtid & 7;            // 0..7
    const int lh = (vtid >> 3) & 3;     // 0..3
    const int ld = vtid >> 5;           // 0..3

    // ---- stage forward-x halo (OOB -> EPS, matching ConstantPad3d(radius-1, eps)) ----
    const float* bbase = batch + (size_t)bb * 32768;
    const float* pbase = preds + (size_t)bb * 8 * 32768;
    for (int v = tid; v < HVOL; v += NT) {
        int hw_ = v % HW;
        int t   = v / HW;
        int hh_ = t % HH;
        int hd_ = t / HH;               // 0..6, forward only
        int f  = hd_ * SXB + hh_ * SYB + hw_;      // swizzled voxel slot
        int gd = d0 + hd_, gh = h0 + hh_ - 3, gw = w0 + hw_ - 3;
        bool in = ((unsigned)gd < 32u) & ((unsigned)gh < 32u) & ((unsigned)gw < 32u);
        int sidx = (gd * 32 + gh) * 32 + gw;
        sB[f] = in ? bbase[sidx] : EPS_F;
        unsigned u[4];
#pragma unroll
        for (int k = 0; k < 4; ++k) {
            float a = in ? pbase[sidx + (2 * k) * 32768]     : 0.f;
            float b = in ? pbase[sidx + (2 * k + 1) * 32768] : 0.f;
            unsigned lo = __half_as_ushort(__float2half(a));
            unsigned hi = __half_as_ushort(__float2half(b));
            u[k] = lo | (hi << 16);
        }
        sPk[f] = make_uint4(u[0], u[1], u[2], u[3]);
    }
    __syncthreads();

    // ---- own voxel values from GLOBAL f32 (full precision for b_own and q) ----
    const int gdo = d0 + ld, gho = h0 + lh, gwo = w0 + lw;
    const int sidx_own = (gdo * 32 + gho) * 32 + gwo;
    const float b_own = bbase[sidx_own];
    float q[8];
#pragma unroll
    for (int k = 0; k < 8; ++k) q[k] = pbase[sidx_own + k * 32768];

    const int vown = ld * SXB + (lh + 3) * SYB + (lw + 3);

    float acc[9];
#pragma unroll
    for (int i = 0; i < 9; ++i) acc[i] = 0.f;

    if (half == 0) accum_pairs<0>(sB, sPk, vown, b_own, acc);
    else           accum_pairs<1>(sB, sPk, vown, b_own, acc);

    // ---- geometric pad sum S over lexicographically NEGATIVE OOB offsets ----
    // (positive-direction pads already counted in acc[8] via EPS-staged halo)
    float S = 0.f;
    const bool border = (d0 < 3) | (h0 < 3) | (h0 + TH > 29) | (w0 < 3) | (w0 + TW > 29);
    if (border && half == 0) {
        constexpr float EXT[10] = {EX0, EX1, 0.f, 0.f, EX4, 0.f, 0.f, 0.f, 0.f, EX9};
        for (int dxi = 0; dxi < 7; ++dxi) {
            const int dx  = dxi - 3;
            const int dxx = dx * dx;
            const bool ind = (unsigned)(gdo + dx) < 32u;
            for (int dyi = 0; dyi < 7; ++dyi) {
                const int dy   = dyi - 3;
                const int c2xy = dxx + dy * dy;
                if (c2xy >= 16) continue;
                const float wxy = __expf((float)c2xy * -0.0625f);
                const bool inxy = ind & ((unsigned)(gho + dy) < 32u);
#pragma unroll
                for (int dzi = 0; dzi < 7; ++dzi) {
                    const int dz  = dzi - 3;
                    const int czz = dz * dz;                 // compile-time
                    const bool neg = (dx < 0) || (dx == 0 && (dy < 0 || (dy == 0 && dz < 0)));
                    const bool valid = ((c2xy + czz) < 16) && neg;
                    const bool inall = inxy & ((unsigned)(gwo + dz) < 32u);
                    S += (valid && !inall) ? wxy * EXT[czz] : 0.f;
                }
            }
        }
    }
    const float db = b_own - EPS_F;
    const float selfpad = (half == 0) ? (1.f + S * __expf(db * db * -0.01f)) : 0.f;

    // ---- per-lane contributions ----
    float vals[16];
#pragma unroll
    for (int k = 0; k < 8; ++k) {
        vals[k]     = q[k] * (2.f * acc[k] + ((half == 0) ? q[k] : 0.f));
        vals[8 + k] = q[k] * (acc[8] + selfpad) + acc[k];
    }

#pragma unroll
    for (int i = 0; i < 16; ++i) {
        float s = vals[i];
        for (int off = 32; off; off >>= 1) s += __shfl_down(s, off);
        vals[i] = s;
    }
    const int wave = tid >> 6;
    const int lane = tid & 63;
    if (lane == 0) {
#pragma unroll
        for (int i = 0; i < 16; ++i) sRed[wave][i] = vals[i];
    }
    __syncthreads();
    if (tid < 16) {
        partials[tid * NBLK + bid] =
            sRed[0][tid] + sRed[1][tid] + sRed[2][tid] + sRed[3][tid];
    }
}

__global__ __launch_bounds__(1024)
void softncuts_finalize(const float* __restrict__ partials,
                        float* __restrict__ out) {
    __shared__ float red[64];
    const int tid = threadIdx.x;          // 0..1023
    const int group = tid >> 4;           // 0..63 = bb*16 + slot
    const int j0 = tid & 15;
    const int slot = group & 15;
    const int bb = group >> 4;

    const float* p = partials + slot * NBLK + bb * 256;
    float s = 0.f;
#pragma unroll
    for (int k = 0; k < 16; ++k) s += p[j0 + 16 * k];
    for (int off = 8; off; off >>= 1) s += __shfl_down(s, off, 16);
    if (j0 == 0) red[group] = s;
    __syncthreads();

    if (tid < 4) {
        float accv = 0.f;
#pragma unroll
        for (int k = 0; k < 8; ++k)
            accv += red[tid * 16 + k] / red[tid * 16 + 8 + k];
        out[tid] = 8.0f - accv;
    }
}

extern "C" void kernel_launch(void* const* d_in, const int* in_sizes, int n_in,
                              void* d_out, int out_size, void* d_ws, size_t ws_size,
                              hipStream_t stream) {
    const float* batch = (const float*)d_in[0];
    const float* preds = (const float*)d_in[1];
    float* out      = (float*)d_out;
    float* partials = (float*)d_ws;   // 16*NBLK floats = 64 KB

    softncuts_main<<<dim3(NBLK), dim3(NT), 0, stream>>>(batch, preds, partials);
    softncuts_finalize<<<dim3(1), dim3(1024), 0, stream>>>(partials, out);
}

// Round 10
// 86.478 us; speedup vs baseline: 2.1047x; 1.0070x over previous
//
#include <hip/hip_runtime.h>
#include <hip/hip_fp16.h>

// SoftNCutsLoss on MI355X — R10.
// batch: (4,1,32,32,32) f32, preds: (4,8,32,32,32) f32 -> out: (4,) f32
//
// R10 = R9 (pairwise symmetry, 125 positive offsets, negative-only pad sum S;
// absmax 0.0) with the inner loop restructured for ILP: constexpr offset/weight
// table, processed in batches of 4 — 8 back-to-back ds_reads (4xb128+4xb32)
// land in ~20 VGPRs, then 4 offsets of math while later reads fly.
// Theory: VGPR 52 across all fast variants = compiler scheduled load->wait->
// compute serially per offset; VALUBusy pinned ~43-52% across 2x occupancy
// (R6 vs R7) is the per-wave serial-dependency signature. launch_bounds(256,4)
// caps at 128 VGPR — room for the batch registers.

#define EPS_F 2.220446049250313e-16f

constexpr int TD = 4, TH = 4, TW = 8;      // tile dims (d,h,w)
constexpr int HD = 7, HH = 10, HW = 14;    // halo: x forward-only +3, y/z +-3
constexpr int HVOL = HD * HH * HW;         // 980 (staging loop bound)
constexpr int SXB = 168;                   // halo d-stride (== 8 mod 32)
constexpr int SYB = 16;                    // halo h-stride
constexpr int NB  = 6 * SXB + 9 * SYB + 13 + 1;  // 1166 voxel slots
constexpr int NT = 256;                    // threads per block (4 waves)
constexpr int NBLK = 1024;                 // 4 batches * 256 tiles

// exp(-s^2/16) for s^2 in {0,1,4,9}
#define EX0 1.0f
#define EX1 0.93941306281347578611f
#define EX4 0.77880078307140486825f
#define EX9 0.56978282473092302544f

__device__ __forceinline__ float2 unpack_h2(unsigned u) {
    __half2 h;
    __builtin_memcpy(&h, &u, 4);
    return __half22float2(h);
}

// ---- compile-time offset/weight tables (positive lexicographic offsets, ----
// ---- split by (dyi+dzi) parity across wave pairs) ----
struct Ent { int off; float w; };
struct Tab { Ent e[64]; int n; };

constexpr Tab make_tab(int half) {
    Tab t{};
    t.n = 0;
    const float ext[10] = {EX0, EX1, 0.f, 0.f, EX4, 0.f, 0.f, 0.f, 0.f, EX9};
    for (int dxq = 0; dxq < 4; ++dxq)
        for (int dyi = 0; dyi < 7; ++dyi)
            for (int dzi = 0; dzi < 7; ++dzi) {
                int dy = dyi - 3, dz = dzi - 3;
                if (dxq == 0) {                  // lexicographic positivity
                    if (dy < 0) continue;
                    if (dy == 0 && dz <= 0) continue;
                }
                int c2 = dxq * dxq + dy * dy + dz * dz;
                if (c2 >= 16) continue;          // ball cutoff
                if (((dyi + dzi) & 1) != half) continue;
                t.e[t.n].off = dxq * SXB + dy * SYB + dz;
                t.e[t.n].w   = ext[dxq * dxq] * ext[dy * dy] * ext[dz * dz];
                ++t.n;
            }
    return t;
}

constexpr Tab TAB0 = make_tab(0);
constexpr Tab TAB1 = make_tab(1);

template <int HALF>
__device__ __forceinline__ void accum_pairs(const float* __restrict__ sB,
                                            const uint4* __restrict__ sPk,
                                            int vown, float b_own,
                                            float acc[9]) {
    constexpr Tab T = HALF ? TAB1 : TAB0;
    constexpr int N = HALF ? TAB1.n : TAB0.n;
    constexpr int N4 = (N / 4) * 4;

#pragma unroll
    for (int i = 0; i < N4; i += 4) {
        float sb[4];
        uint4 pk[4];
#pragma unroll
        for (int j = 0; j < 4; ++j) {            // 8 ds_reads issued together
            const int nv = vown + T.e[i + j].off;
            sb[j] = sB[nv];
            pk[j] = sPk[nv];
        }
#pragma unroll
        for (int j = 0; j < 4; ++j) {
            const float w = T.e[i + j].w;        // compile-time literal
            const float d = b_own - sb[j];
            const float aff = __expf(d * d * -0.01f) * w;
            acc[8] += aff;
            const float2 f01 = unpack_h2(pk[j].x);
            const float2 f23 = unpack_h2(pk[j].y);
            const float2 f45 = unpack_h2(pk[j].z);
            const float2 f67 = unpack_h2(pk[j].w);
            acc[0] += aff * f01.x; acc[1] += aff * f01.y;
            acc[2] += aff * f23.x; acc[3] += aff * f23.y;
            acc[4] += aff * f45.x; acc[5] += aff * f45.y;
            acc[6] += aff * f67.x; acc[7] += aff * f67.y;
        }
    }
#pragma unroll
    for (int i = N4; i < N; ++i) {               // remainder (<=3)
        const int nv = vown + T.e[i].off;
        const float sb = sB[nv];
        const uint4 pk = sPk[nv];
        const float d = b_own - sb;
        const float aff = __expf(d * d * -0.01f) * T.e[i].w;
        acc[8] += aff;
        const float2 f01 = unpack_h2(pk.x);
        const float2 f23 = unpack_h2(pk.y);
        const float2 f45 = unpack_h2(pk.z);
        const float2 f67 = unpack_h2(pk.w);
        acc[0] += aff * f01.x; acc[1] += aff * f01.y;
        acc[2] += aff * f23.x; acc[3] += aff * f23.y;
        acc[4] += aff * f45.x; acc[5] += aff * f45.y;
        acc[6] += aff * f67.x; acc[7] += aff * f67.y;
    }
}

__global__ __launch_bounds__(NT, 4)
void softncuts_main(const float* __restrict__ batch,
                    const float* __restrict__ preds,
                    float* __restrict__ partials) {
    __shared__ float sB[NB];            // batch halo, f32
    __shared__ uint4 sPk[NB];           // preds halo, 8 x f16 packed per voxel
    __shared__ float sRed[4][16];

    const int bid  = blockIdx.x;
    const int bb   = bid >> 8;          // batch index 0..3
    const int tile = bid & 255;
    const int tw = tile & 3;            // 0..3  -> w0 = tw*8
    const int th = (tile >> 2) & 7;     // 0..7  -> h0 = th*4
    const int td = tile >> 5;           // 0..7  -> d0 = td*4
    const int d0 = td * TD, h0 = th * TH, w0 = tw * TW;

    const int tid  = threadIdx.x;
    const int half = tid >> 7;          // wave-pair-uniform 0/1
    const int vtid = tid & 127;
    const int lw = vtid & 7;            // 0..7
    const int lh = (vtid >> 3) & 3;     // 0..3
    const int ld = vtid >> 5;           // 0..3

    // ---- stage forward-x halo (OOB -> EPS, matching ConstantPad3d(radius-1, eps)) ----
    const float* bbase = batch + (size_t)bb * 32768;
    const float* pbase = preds + (size_t)bb * 8 * 32768;
    for (int v = tid; v < HVOL; v += NT) {
        int hw_ = v % HW;
        int t   = v / HW;
        int hh_ = t % HH;
        int hd_ = t / HH;               // 0..6, forward only
        int f  = hd_ * SXB + hh_ * SYB + hw_;      // swizzled voxel slot
        int gd = d0 + hd_, gh = h0 + hh_ - 3, gw = w0 + hw_ - 3;
        bool in = ((unsigned)gd < 32u) & ((unsigned)gh < 32u) & ((unsigned)gw < 32u);
        int sidx = (gd * 32 + gh) * 32 + gw;
        sB[f] = in ? bbase[sidx] : EPS_F;
        unsigned u[4];
#pragma unroll
        for (int k = 0; k < 4; ++k) {
            float a = in ? pbase[sidx + (2 * k) * 32768]     : 0.f;
            float b = in ? pbase[sidx + (2 * k + 1) * 32768] : 0.f;
            unsigned lo = __half_as_ushort(__float2half(a));
            unsigned hi = __half_as_ushort(__float2half(b));
            u[k] = lo | (hi << 16);
        }
        sPk[f] = make_uint4(u[0], u[1], u[2], u[3]);
    }
    __syncthreads();

    // ---- own voxel values from GLOBAL f32 (full precision for b_own and q) ----
    const int gdo = d0 + ld, gho = h0 + lh, gwo = w0 + lw;
    const int sidx_own = (gdo * 32 + gho) * 32 + gwo;
    const float b_own = bbase[sidx_own];
    float q[8];
#pragma unroll
    for (int k = 0; k < 8; ++k) q[k] = pbase[sidx_own + k * 32768];

    const int vown = ld * SXB + (lh + 3) * SYB + (lw + 3);

    float acc[9];
#pragma unroll
    for (int i = 0; i < 9; ++i) acc[i] = 0.f;

    if (half == 0) accum_pairs<0>(sB, sPk, vown, b_own, acc);
    else           accum_pairs<1>(sB, sPk, vown, b_own, acc);

    // ---- geometric pad sum S over lexicographically NEGATIVE OOB offsets ----
    // (positive-direction pads already counted in acc[8] via EPS-staged halo)
    float S = 0.f;
    const bool border = (d0 < 3) | (h0 < 3) | (h0 + TH > 29) | (w0 < 3) | (w0 + TW > 29);
    if (border && half == 0) {
        constexpr float EXT[10] = {EX0, EX1, 0.f, 0.f, EX4, 0.f, 0.f, 0.f, 0.f, EX9};
        for (int dxi = 0; dxi < 7; ++dxi) {
            const int dx  = dxi - 3;
            const int dxx = dx * dx;
            const bool ind = (unsigned)(gdo + dx) < 32u;
            for (int dyi = 0; dyi < 7; ++dyi) {
                const int dy   = dyi - 3;
                const int c2xy = dxx + dy * dy;
                if (c2xy >= 16) continue;
                const float wxy = __expf((float)c2xy * -0.0625f);
                const bool inxy = ind & ((unsigned)(gho + dy) < 32u);
#pragma unroll
                for (int dzi = 0; dzi < 7; ++dzi) {
                    const int dz  = dzi - 3;
                    const int czz = dz * dz;                 // compile-time
                    const bool neg = (dx < 0) || (dx == 0 && (dy < 0 || (dy == 0 && dz < 0)));
                    const bool valid = ((c2xy + czz) < 16) && neg;
                    const bool inall = inxy & ((unsigned)(gwo + dz) < 32u);
                    S += (valid && !inall) ? wxy * EXT[czz] : 0.f;
                }
            }
        }
    }
    const float db = b_own - EPS_F;
    const float selfpad = (half == 0) ? (1.f + S * __expf(db * db * -0.01f)) : 0.f;

    // ---- per-lane contributions ----
    float vals[16];
#pragma unroll
    for (int k = 0; k < 8; ++k) {
        vals[k]     = q[k] * (2.f * acc[k] + ((half == 0) ? q[k] : 0.f));
        vals[8 + k] = q[k] * (acc[8] + selfpad) + acc[k];
    }

#pragma unroll
    for (int i = 0; i < 16; ++i) {
        float s = vals[i];
        for (int off = 32; off; off >>= 1) s += __shfl_down(s, off);
        vals[i] = s;
    }
    const int wave = tid >> 6;
    const int lane = tid & 63;
    if (lane == 0) {
#pragma unroll
        for (int i = 0; i < 16; ++i) sRed[wave][i] = vals[i];
    }
    __syncthreads();
    if (tid < 16) {
        partials[tid * NBLK + bid] =
            sRed[0][tid] + sRed[1][tid] + sRed[2][tid] + sRed[3][tid];
    }
}

__global__ __launch_bounds__(1024)
void softncuts_finalize(const float* __restrict__ partials,
                        float* __restrict__ out) {
    __shared__ float red[64];
    const int tid = threadIdx.x;          // 0..1023
    const int group = tid >> 4;           // 0..63 = bb*16 + slot
    const int j0 = tid & 15;
    const int slot = group & 15;
    const int bb = group >> 4;

    const float* p = partials + slot * NBLK + bb * 256;
    float s = 0.f;
#pragma unroll
    for (int k = 0; k < 16; ++k) s += p[j0 + 16 * k];
    for (int off = 8; off; off >>= 1) s += __shfl_down(s, off, 16);
    if (j0 == 0) red[group] = s;
    __syncthreads();

    if (tid < 4) {
        float accv = 0.f;
#pragma unroll
        for (int k = 0; k < 8; ++k)
            accv += red[tid * 16 + k] / red[tid * 16 + 8 + k];
        out[tid] = 8.0f - accv;
    }
}

extern "C" void kernel_launch(void* const* d_in, const int* in_sizes, int n_in,
                              void* d_out, int out_size, void* d_ws, size_t ws_size,
                              hipStream_t stream) {
    const float* batch = (const float*)d_in[0];
    const float* preds = (const float*)d_in[1];
    float* out      = (float*)d_out;
    float* partials = (float*)d_ws;   // 16*NBLK floats = 64 KB

    softncuts_main<<<dim3(NBLK), dim3(NT), 0, stream>>>(batch, preds, partials);
    softncuts_finalize<<<dim3(1), dim3(1024), 0, stream>>>(partials, out);
}

// Round 11
// 85.959 us; speedup vs baseline: 2.1174x; 1.0060x over previous
//
#include <hip/hip_runtime.h>
#include <hip/hip_fp16.h>

// SoftNCutsLoss on MI355X — R11.
// batch: (4,1,32,32,32) f32, preds: (4,8,32,32,32) f32 -> out: (4,) f32
//
// R11 model: main kernel is per-wave ISSUE-bound (~78 cyc/wave-offset measured;
// ~26 instr/offset ~= 55-60 issue cyc; VALUBusy under-reports via gfx94x
// formula fallback). All throughput/latency levers were neutral (R3 banks,
// R6 LDS width, R7 occupancy, R10 ILP); only the R9 work cut moved time.
// So: cut instructions per offset ~26 -> ~16:
//  1) weight folded into exponent: aff = exp2(d^2*K1 + c2*K2), K2-term a
//     compile-time literal per offset -> one v_fma + v_exp (deletes 2 muls).
//  2) class accumulate as fmaf(aff, __half2float(h), acc) on scalar halves ->
//     v_fma_mix_f32 fusion (deletes 8 v_cvt_f32_f16).
// Skeleton (pairwise symmetry, 125 positive offsets, negative-only pad S,
// forward-x halo, f16-packed preds, two-kernel reduction) = R9/R10, absmax 0.0.

#define EPS_F 2.220446049250313e-16f

constexpr int TD = 4, TH = 4, TW = 8;      // tile dims (d,h,w)
constexpr int HD = 7, HH = 10, HW = 14;    // halo: x forward-only +3, y/z +-3
constexpr int HVOL = HD * HH * HW;         // 980 (staging loop bound)
constexpr int SXB = 168;                   // halo d-stride (== 8 mod 32)
constexpr int SYB = 16;                    // halo h-stride
constexpr int NB  = 6 * SXB + 9 * SYB + 13 + 1;  // 1166 voxel slots
constexpr int NT = 256;                    // threads per block (4 waves)
constexpr int NBLK = 1024;                 // 4 batches * 256 tiles

// exp(-s^2/16) for s^2 in {0,1,4,9} (pad-S path only)
#define EX0 1.0f
#define EX1 0.93941306281347578611f
#define EX4 0.77880078307140486825f
#define EX9 0.56978282473092302544f

// exponent-folding constants: aff = exp2(d2*K1 + c2*K2)
#define K1F (-0.014426950408889634f)       // -0.01 * log2(e)
#define K2F (-0.09016844005556021f)        // -log2(e)/16

// ---- compile-time offset/exponent-bias tables (positive lexicographic ----
// ---- offsets, split by (dyi+dzi) parity across wave pairs) ----
struct Ent { int off; float lw; };         // lw = c2 * K2 (compile-time)
struct Tab { Ent e[64]; int n; };

constexpr Tab make_tab(int half) {
    Tab t{};
    t.n = 0;
    for (int dxq = 0; dxq < 4; ++dxq)
        for (int dyi = 0; dyi < 7; ++dyi)
            for (int dzi = 0; dzi < 7; ++dzi) {
                int dy = dyi - 3, dz = dzi - 3;
                if (dxq == 0) {                  // lexicographic positivity
                    if (dy < 0) continue;
                    if (dy == 0 && dz <= 0) continue;
                }
                int c2 = dxq * dxq + dy * dy + dz * dz;
                if (c2 >= 16) continue;          // ball cutoff
                if (((dyi + dzi) & 1) != half) continue;
                t.e[t.n].off = dxq * SXB + dy * SYB + dz;
                t.e[t.n].lw  = (float)c2 * K2F;
                ++t.n;
            }
    return t;
}

constexpr Tab TAB0 = make_tab(0);
constexpr Tab TAB1 = make_tab(1);

template <int HALF>
__device__ __forceinline__ void accum_pairs(const float* __restrict__ sB,
                                            const uint4* __restrict__ sPk,
                                            int vown, float b_own,
                                            float acc[9]) {
    constexpr Tab T = HALF ? TAB1 : TAB0;
    constexpr int N = HALF ? TAB1.n : TAB0.n;
    constexpr int N4 = (N / 4) * 4;

#pragma unroll
    for (int i = 0; i < N4; i += 4) {
        float sb[4];
        uint4 pk[4];
#pragma unroll
        for (int j = 0; j < 4; ++j) {            // 8 ds_reads issued together
            const int nv = vown + T.e[i + j].off;
            sb[j] = sB[nv];
            pk[j] = sPk[nv];
        }
#pragma unroll
        for (int j = 0; j < 4; ++j) {
            const float d = b_own - sb[j];
            // aff = w * exp(-d^2/100) = exp2(d^2*K1 + c2*K2); lw is a literal
            const float aff =
                __builtin_amdgcn_exp2f(__builtin_fmaf(d * d, K1F, T.e[i + j].lw));
            acc[8] += aff;
            __half2 h[4];
            __builtin_memcpy(h, &pk[j], 16);
            // fmaf(f32, cvt(f16), f32) -> v_fma_mix_f32 (no separate cvt)
            acc[0] = __builtin_fmaf(aff, __half2float(__low2half(h[0])),  acc[0]);
            acc[1] = __builtin_fmaf(aff, __half2float(__high2half(h[0])), acc[1]);
            acc[2] = __builtin_fmaf(aff, __half2float(__low2half(h[1])),  acc[2]);
            acc[3] = __builtin_fmaf(aff, __half2float(__high2half(h[1])), acc[3]);
            acc[4] = __builtin_fmaf(aff, __half2float(__low2half(h[2])),  acc[4]);
            acc[5] = __builtin_fmaf(aff, __half2float(__high2half(h[2])), acc[5]);
            acc[6] = __builtin_fmaf(aff, __half2float(__low2half(h[3])),  acc[6]);
            acc[7] = __builtin_fmaf(aff, __half2float(__high2half(h[3])), acc[7]);
        }
    }
#pragma unroll
    for (int i = N4; i < N; ++i) {               // remainder (<=3)
        const int nv = vown + T.e[i].off;
        const float sb = sB[nv];
        const uint4 pk = sPk[nv];
        const float d = b_own - sb;
        const float aff =
            __builtin_amdgcn_exp2f(__builtin_fmaf(d * d, K1F, T.e[i].lw));
        acc[8] += aff;
        __half2 h[4];
        __builtin_memcpy(h, &pk, 16);
        acc[0] = __builtin_fmaf(aff, __half2float(__low2half(h[0])),  acc[0]);
        acc[1] = __builtin_fmaf(aff, __half2float(__high2half(h[0])), acc[1]);
        acc[2] = __builtin_fmaf(aff, __half2float(__low2half(h[1])),  acc[2]);
        acc[3] = __builtin_fmaf(aff, __half2float(__high2half(h[1])), acc[3]);
        acc[4] = __builtin_fmaf(aff, __half2float(__low2half(h[2])),  acc[4]);
        acc[5] = __builtin_fmaf(aff, __half2float(__high2half(h[2])), acc[5]);
        acc[6] = __builtin_fmaf(aff, __half2float(__low2half(h[3])),  acc[6]);
        acc[7] = __builtin_fmaf(aff, __half2float(__high2half(h[3])), acc[7]);
    }
}

__global__ __launch_bounds__(NT, 4)
void softncuts_main(const float* __restrict__ batch,
                    const float* __restrict__ preds,
                    float* __restrict__ partials) {
    __shared__ float sB[NB];            // batch halo, f32
    __shared__ uint4 sPk[NB];           // preds halo, 8 x f16 packed per voxel
    __shared__ float sRed[4][16];

    const int bid  = blockIdx.x;
    const int bb   = bid >> 8;          // batch index 0..3
    const int tile = bid & 255;
    const int tw = tile & 3;            // 0..3  -> w0 = tw*8
    const int th = (tile >> 2) & 7;     // 0..7  -> h0 = th*4
    const int td = tile >> 5;           // 0..7  -> d0 = td*4
    const int d0 = td * TD, h0 = th * TH, w0 = tw * TW;

    const int tid  = threadIdx.x;
    const int half = tid >> 7;          // wave-pair-uniform 0/1
    const int vtid = tid & 127;
    const int lw = vtid & 7;            // 0..7
    const int lh = (vtid >> 3) & 3;     // 0..3
    const int ld = vtid >> 5;           // 0..3

    // ---- stage forward-x halo (OOB -> EPS, matching ConstantPad3d(radius-1, eps)) ----
    const float* bbase = batch + (size_t)bb * 32768;
    const float* pbase = preds + (size_t)bb * 8 * 32768;
    for (int v = tid; v < HVOL; v += NT) {
        int hw_ = v % HW;
        int t   = v / HW;
        int hh_ = t % HH;
        int hd_ = t / HH;               // 0..6, forward only
        int f  = hd_ * SXB + hh_ * SYB + hw_;      // swizzled voxel slot
        int gd = d0 + hd_, gh = h0 + hh_ - 3, gw = w0 + hw_ - 3;
        bool in = ((unsigned)gd < 32u) & ((unsigned)gh < 32u) & ((unsigned)gw < 32u);
        int sidx = (gd * 32 + gh) * 32 + gw;
        sB[f] = in ? bbase[sidx] : EPS_F;
        unsigned u[4];
#pragma unroll
        for (int k = 0; k < 4; ++k) {
            float a = in ? pbase[sidx + (2 * k) * 32768]     : 0.f;
            float b = in ? pbase[sidx + (2 * k + 1) * 32768] : 0.f;
            unsigned lo = __half_as_ushort(__float2half(a));
            unsigned hi = __half_as_ushort(__float2half(b));
            u[k] = lo | (hi << 16);
        }
        sPk[f] = make_uint4(u[0], u[1], u[2], u[3]);
    }
    __syncthreads();

    // ---- own voxel values from GLOBAL f32 (full precision for b_own and q) ----
    const int gdo = d0 + ld, gho = h0 + lh, gwo = w0 + lw;
    const int sidx_own = (gdo * 32 + gho) * 32 + gwo;
    const float b_own = bbase[sidx_own];
    float q[8];
#pragma unroll
    for (int k = 0; k < 8; ++k) q[k] = pbase[sidx_own + k * 32768];

    const int vown = ld * SXB + (lh + 3) * SYB + (lw + 3);

    float acc[9];
#pragma unroll
    for (int i = 0; i < 9; ++i) acc[i] = 0.f;

    if (half == 0) accum_pairs<0>(sB, sPk, vown, b_own, acc);
    else           accum_pairs<1>(sB, sPk, vown, b_own, acc);

    // ---- geometric pad sum S over lexicographically NEGATIVE OOB offsets ----
    // (positive-direction pads already counted in acc[8] via EPS-staged halo)
    float S = 0.f;
    const bool border = (d0 < 3) | (h0 < 3) | (h0 + TH > 29) | (w0 < 3) | (w0 + TW > 29);
    if (border && half == 0) {
        constexpr float EXT[10] = {EX0, EX1, 0.f, 0.f, EX4, 0.f, 0.f, 0.f, 0.f, EX9};
        for (int dxi = 0; dxi < 7; ++dxi) {
            const int dx  = dxi - 3;
            const int dxx = dx * dx;
            const bool ind = (unsigned)(gdo + dx) < 32u;
            for (int dyi = 0; dyi < 7; ++dyi) {
                const int dy   = dyi - 3;
                const int c2xy = dxx + dy * dy;
                if (c2xy >= 16) continue;
                const float wxy = __expf((float)c2xy * -0.0625f);
                const bool inxy = ind & ((unsigned)(gho + dy) < 32u);
#pragma unroll
                for (int dzi = 0; dzi < 7; ++dzi) {
                    const int dz  = dzi - 3;
                    const int czz = dz * dz;                 // compile-time
                    const bool neg = (dx < 0) || (dx == 0 && (dy < 0 || (dy == 0 && dz < 0)));
                    const bool valid = ((c2xy + czz) < 16) && neg;
                    const bool inall = inxy & ((unsigned)(gwo + dz) < 32u);
                    S += (valid && !inall) ? wxy * EXT[czz] : 0.f;
                }
            }
        }
    }
    const float db = b_own - EPS_F;
    const float selfpad = (half == 0) ? (1.f + S * __expf(db * db * -0.01f)) : 0.f;

    // ---- per-lane contributions ----
    float vals[16];
#pragma unroll
    for (int k = 0; k < 8; ++k) {
        vals[k]     = q[k] * (2.f * acc[k] + ((half == 0) ? q[k] : 0.f));
        vals[8 + k] = q[k] * (acc[8] + selfpad) + acc[k];
    }

#pragma unroll
    for (int i = 0; i < 16; ++i) {
        float s = vals[i];
        for (int off = 32; off; off >>= 1) s += __shfl_down(s, off);
        vals[i] = s;
    }
    const int wave = tid >> 6;
    const int lane = tid & 63;
    if (lane == 0) {
#pragma unroll
        for (int i = 0; i < 16; ++i) sRed[wave][i] = vals[i];
    }
    __syncthreads();
    if (tid < 16) {
        partials[tid * NBLK + bid] =
            sRed[0][tid] + sRed[1][tid] + sRed[2][tid] + sRed[3][tid];
    }
}

__global__ __launch_bounds__(1024)
void softncuts_finalize(const float* __restrict__ partials,
                        float* __restrict__ out) {
    __shared__ float red[64];
    const int tid = threadIdx.x;          // 0..1023
    const int group = tid >> 4;           // 0..63 = bb*16 + slot
    const int j0 = tid & 15;
    const int slot = group & 15;
    const int bb = group >> 4;

    const float* p = partials + slot * NBLK + bb * 256;
    float s = 0.f;
#pragma unroll
    for (int k = 0; k < 16; ++k) s += p[j0 + 16 * k];
    for (int off = 8; off; off >>= 1) s += __shfl_down(s, off, 16);
    if (j0 == 0) red[group] = s;
    __syncthreads();

    if (tid < 4) {
        float accv = 0.f;
#pragma unroll
        for (int k = 0; k < 8; ++k)
            accv += red[tid * 16 + k] / red[tid * 16 + 8 + k];
        out[tid] = 8.0f - accv;
    }
}

extern "C" void kernel_launch(void* const* d_in, const int* in_sizes, int n_in,
                              void* d_out, int out_size, void* d_ws, size_t ws_size,
                              hipStream_t stream) {
    const float* batch = (const float*)d_in[0];
    const float* preds = (const float*)d_in[1];
    float* out      = (float*)d_out;
    float* partials = (float*)d_ws;   // 16*NBLK floats = 64 KB

    softncuts_main<<<dim3(NBLK), dim3(NT), 0, stream>>>(batch, preds, partials);
    softncuts_finalize<<<dim3(1), dim3(1024), 0, stream>>>(partials, out);
}